// Round 6
// baseline (424.961 us; speedup 1.0000x reference)
//
#include <hip/hip_runtime.h>

typedef _Float16 f16x8 __attribute__((ext_vector_type(8)));
typedef float f32x4 __attribute__((ext_vector_type(4)));
typedef unsigned long long u64;

#define NB 192

// ---- IF-coherent (L1/L2-bypassing) accessors: relaxed system-scope atomics.
__device__ __forceinline__ float ldw(const float* p) {
    return __uint_as_float(__hip_atomic_load((unsigned*)p, __ATOMIC_RELAXED,
                                             __HIP_MEMORY_SCOPE_SYSTEM));
}
__device__ __forceinline__ void stw(float* p, float x) {
    __hip_atomic_store((unsigned*)p, __float_as_uint(x), __ATOMIC_RELAXED,
                       __HIP_MEMORY_SCOPE_SYSTEM);
}
__device__ __forceinline__ u64 ld64(const u64* p) {
    return __hip_atomic_load(p, __ATOMIC_RELAXED, __HIP_MEMORY_SCOPE_SYSTEM);
}
__device__ __forceinline__ void postf(int* fl, int bid) {
    asm volatile("s_waitcnt vmcnt(0) lgkmcnt(0)" ::: "memory");
    __hip_atomic_store(fl + bid, 1, __ATOMIC_RELAXED, __HIP_MEMORY_SCOPE_SYSTEM);
}
__device__ __forceinline__ void gbar(int* fl, int bid, int tid) {
    __syncthreads();
    if (tid == 0) postf(fl, bid);
    if (tid < 64) {
        int* p0 = fl + tid;
        for (;;) {
            int ok = (__hip_atomic_load(p0, __ATOMIC_RELAXED, __HIP_MEMORY_SCOPE_SYSTEM) == 1)
                   & (__hip_atomic_load(p0+64, __ATOMIC_RELAXED, __HIP_MEMORY_SCOPE_SYSTEM) == 1)
                   & (__hip_atomic_load(p0+128, __ATOMIC_RELAXED, __HIP_MEMORY_SCOPE_SYSTEM) == 1);
            if (__all(ok)) break;
            __builtin_amdgcn_s_sleep(2);
        }
    }
    __syncthreads();
    asm volatile("" ::: "memory");
}

__global__ void __launch_bounds__(512) mega4_k(
    const float* __restrict__ sx, const int* __restrict__ sy,
    const float* __restrict__ qx, const int* __restrict__ qy,
    const float* __restrict__ k1, const float* __restrict__ bc1,
    const float* __restrict__ k2, const float* __restrict__ bc2,
    const float* __restrict__ k3, const float* __restrict__ bc3,
    const float* __restrict__ Wlog, const float* __restrict__ blog,
    const float* __restrict__ Wg1, const float* __restrict__ bg1,
    const float* __restrict__ Wg2, const float* __restrict__ bg2,
    const float* __restrict__ Wf1, const float* __restrict__ bf1,
    const float* __restrict__ Wf2, const float* __restrict__ bf2,
    float* __restrict__ ws, float* __restrict__ out)
{
    __shared__ __align__(16) float smem[32768];   // 128 KB
    const int tid = threadIdx.x;
    const int bid = blockIdx.x;

    float* feat1 = ws;                      // 786432
    float* feat2 = feat1 + 786432;          // 294912
    float* feat3 = feat2 + 294912;          // 98304
    float* mf    = feat3 + 98304;           // 1536
    float* rv    = mf + 1536;               // 64
    float* Pmg   = rv + 64;                 // 160
    unsigned* U32 = (unsigned*)(Pmg + 160); // 98304
    unsigned* V32 = U32 + 98304;            // 98304
    int* flag0 = (int*)(V32 + 98304);
    int* flag1 = flag0 + 192;
    int* flag2 = flag1 + 192;
    int* flag3 = flag2 + 192;
    int* flagB = flag3 + 192;

    // ================= P1: conv1 (192 blocks: img x 8 oc-quads), cached input
    {
        int n = bid >> 3, ocq = bid & 7;
        int bi = n / 6, si = n % 6;
        const float* inp = (si < 5) ? sx + (size_t)((bi*5+si)*3)*4096
                                    : qx + (size_t)(bi*3)*4096;
        #pragma unroll
        for (int half = 0; half < 2; half++) {
            int px = tid + half*512;
            int oy = px >> 5, ox = px & 31;
            float tap[27];
            #pragma unroll
            for (int ic = 0; ic < 3; ic++)
                #pragma unroll
                for (int dy = 0; dy < 3; dy++)
                    #pragma unroll
                    for (int dx = 0; dx < 3; dx++) {
                        int iy = 2*oy+dy, ix = 2*ox+dx;
                        tap[ic*9+dy*3+dx] = (iy < 64 && ix < 64) ? inp[ic*4096 + iy*64 + ix] : 0.f;
                    }
            #pragma unroll
            for (int l = 0; l < 4; l++) {
                int oc = ocq*4 + l;
                float acc = bc1[oc];
                #pragma unroll
                for (int t = 0; t < 27; t++) acc += tap[t]*k1[oc*27 + t];
                stw(&feat1[(size_t)(n*32+oc)*1024 + px], fmaxf(acc, 0.f));
            }
        }
    }
    gbar(flag0, bid, tid);

    // ================= P2: conv2 (144 blocks: img x 6 oc-groups of 8)
    if (bid < 144) {
        int img = bid / 6, ocg = bid % 6;
        // stage feat1 image (32768 f32 = 16384 u64), swizzled quads, batched
        const u64* src = (const u64*)(feat1 + (size_t)img*32768);
        for (int b = 0; b < 4; b++) {
            u64 t[8];
            #pragma unroll
            for (int j = 0; j < 8; j++) t[j] = ld64(&src[b*4096 + j*512 + tid]);
            #pragma unroll
            for (int j = 0; j < 8; j++) {
                int d = (b*4096 + j*512 + tid)*2;
                int ic = d >> 10, r = d & 1023, iy = r >> 5, ix = r & 31;
                int la = (ic<<10) + (iy<<5) + (((((ix>>2)) ^ ((iy>>1)&7))<<2) | (ix&3));
                ((u64*)smem)[la>>1] = t[j];
            }
        }
        __syncthreads();
        int oy = tid & 15, ocl = (tid>>4) & 7, ich = tid >> 7;   // ich 0..3
        int oc = ocg*8 + ocl;
        float acc[16];
        #pragma unroll
        for (int x = 0; x < 16; x++) acc[x] = 0.f;
        for (int ic = ich*8; ic < ich*8+8; ic++) {
            #pragma unroll
            for (int dy = 0; dy < 3; dy++) {
                int iy = 2*oy + dy;
                float row[33];
                if (iy < 32) {
                    int sw = (iy>>1) & 7;
                    #pragma unroll
                    for (int q = 0; q < 8; q++) {
                        f32x4 v = *(const f32x4*)&smem[(ic<<10) + (iy<<5) + ((q^sw)<<2)];
                        row[q*4] = v[0]; row[q*4+1] = v[1]; row[q*4+2] = v[2]; row[q*4+3] = v[3];
                    }
                    row[32] = 0.f;
                } else {
                    #pragma unroll
                    for (int x = 0; x < 33; x++) row[x] = 0.f;
                }
                const float* wp = k2 + (size_t)oc*288 + ic*9 + dy*3;
                float w0 = wp[0], w1 = wp[1], w2 = wp[2];
                #pragma unroll
                for (int ox = 0; ox < 16; ox++)
                    acc[ox] += row[2*ox]*w0 + row[2*ox+1]*w1 + row[2*ox+2]*w2;
            }
        }
        __syncthreads();
        // partials: flat = ich*2048 + ocl*256 + oy*16 + ox
        #pragma unroll
        for (int q = 0; q < 4; q++)
            *(f32x4*)&smem[ich*2048 + ocl*256 + oy*16 + q*4] =
                (f32x4){acc[q*4], acc[q*4+1], acc[q*4+2], acc[q*4+3]};
        __syncthreads();
        #pragma unroll
        for (int r = 0; r < 4; r++) {
            int o = r*512 + tid;
            float s = smem[o] + smem[2048+o] + smem[4096+o] + smem[6144+o];
            int ocl2 = o >> 8, px = o & 255;
            s += bc2[ocg*8 + ocl2];
            stw(&feat2[(size_t)(img*48 + ocg*8 + ocl2)*256 + px], fmaxf(s, 0.f));
        }
    }
    gbar(flag1, bid, tid);

    // ================= P3: conv3 + mean-pool (192 blocks: img x 8 oc-groups of 8)
    {
        int img = bid >> 3, ocg = bid & 7;
        __syncthreads();
        const u64* src = (const u64*)(feat2 + (size_t)img*12288);
        for (int b = 0; b < 2; b++) {
            u64 t[8];
            #pragma unroll
            for (int j = 0; j < 8; j++) {
                int idx = b*4096 + j*512 + tid;
                if (idx < 6144) t[j] = ld64(&src[idx]);
            }
            #pragma unroll
            for (int j = 0; j < 8; j++) {
                int idx = b*4096 + j*512 + tid;
                if (idx < 6144) {
                    int d = idx*2;
                    int ic = d >> 8, r = d & 255, iy = r >> 4, ix = r & 15;
                    int la = (ic<<8) + (iy<<4) + (((((ix>>2)) ^ ((iy>>1)&3))<<2) | (ix&3));
                    ((u64*)smem)[la>>1] = t[j];
                }
            }
        }
        __syncthreads();
        int oy = tid & 7, ocl = (tid>>3) & 7, ich = tid >> 6;   // ich 0..7, 6 ic each
        int oc = ocg*8 + ocl;
        float acc[8];
        #pragma unroll
        for (int x = 0; x < 8; x++) acc[x] = 0.f;
        for (int ic = ich*6; ic < ich*6+6; ic++) {
            #pragma unroll
            for (int dy = 0; dy < 3; dy++) {
                int iy = 2*oy + dy;
                float row[17];
                if (iy < 16) {
                    int sw = (iy>>1) & 3;
                    #pragma unroll
                    for (int q = 0; q < 4; q++) {
                        f32x4 v = *(const f32x4*)&smem[(ic<<8) + (iy<<4) + ((q^sw)<<2)];
                        row[q*4] = v[0]; row[q*4+1] = v[1]; row[q*4+2] = v[2]; row[q*4+3] = v[3];
                    }
                    row[16] = 0.f;
                } else {
                    #pragma unroll
                    for (int x = 0; x < 17; x++) row[x] = 0.f;
                }
                const float* wp = k3 + (size_t)oc*432 + ic*9 + dy*3;
                float w0 = wp[0], w1 = wp[1], w2 = wp[2];
                #pragma unroll
                for (int ox = 0; ox < 8; ox++)
                    acc[ox] += row[2*ox]*w0 + row[2*ox+1]*w1 + row[2*ox+2]*w2;
            }
        }
        __syncthreads();
        // partials: flat = ich*512 + ocl*64 + oy*8
        *(f32x4*)&smem[ich*512 + ocl*64 + oy*8]     = (f32x4){acc[0],acc[1],acc[2],acc[3]};
        *(f32x4*)&smem[ich*512 + ocl*64 + oy*8 + 4] = (f32x4){acc[4],acc[5],acc[6],acc[7]};
        __syncthreads();
        {
            int ocl2 = tid >> 6, px = tid & 63;
            float s = bc3[ocg*8 + ocl2];
            #pragma unroll
            for (int h = 0; h < 8; h++) s += smem[h*512 + tid];
            float r0 = fmaxf(s, 0.f);
            stw(&feat3[(size_t)(img*64 + ocg*8 + ocl2)*64 + px], r0);
            #pragma unroll
            for (int off = 32; off >= 1; off >>= 1) r0 += __shfl_xor(r0, off, 64);
            if (px == 0) stw(&mf[img*64 + ocg*8 + ocl2], r0 * (1.f/64.f));
        }
    }
    gbar(flag2, bid, tid);

    // ================= P4: uv (48 blocks) + cls (blocks 48..71)
    if (bid < 48) {
        int bs = bid >> 1, ph = bid & 1;
        __syncthreads();
        const u64* src = (const u64*)(feat3 + (size_t)bs*4096);
        {
            u64 t[4];
            #pragma unroll
            for (int j = 0; j < 4; j++) t[j] = ld64(&src[j*512 + tid]);
            #pragma unroll
            for (int j = 0; j < 4; j++) ((u64*)smem)[j*512 + tid] = t[j];
        }
        __syncthreads();
        int cp = tid & 63;             // cols 2cp, 2cp+1
        int sel = (tid >> 6) & 1;      // 0=u 1=v
        int pq = tid >> 7;             // 0..3
        int pbase = ph*32 + pq*8;
        float acc0[8], acc1[8];
        float b0 = sel ? bg1[2*cp] : 0.f;
        float b1 = sel ? bg1[2*cp+1] : 0.f;
        #pragma unroll
        for (int k = 0; k < 8; k++) { acc0[k] = b0; acc1[k] = b1; }
        const float* Wc = Wg1 + sel*66*128 + 2*cp;
        for (int c = 0; c < 64; c++) {
            float w0 = Wc[c*128], w1 = Wc[c*128 + 1];
            #pragma unroll
            for (int k = 0; k < 8; k++) {
                float a = smem[c*64 + pbase + k];
                acc0[k] += a*w0; acc1[k] += a*w1;
            }
        }
        #pragma unroll
        for (int c = 64; c < 66; c++) {
            float w0 = Wc[c*128], w1 = Wc[c*128 + 1];
            #pragma unroll
            for (int k = 0; k < 8; k++) {
                int p = pbase + k;
                float a = (c == 64) ? (float)(p>>3)*0.125f : (float)(p&7)*0.125f;
                acc0[k] += a*w0; acc1[k] += a*w1;
            }
        }
        unsigned* dst = sel ? V32 : U32;
        #pragma unroll
        for (int k = 0; k < 8; k++) {
            int p = pbase + k;
            unsigned lo = (unsigned)__builtin_bit_cast(unsigned short, (_Float16)acc0[k]);
            unsigned hi = (unsigned)__builtin_bit_cast(unsigned short, (_Float16)acc1[k]);
            __hip_atomic_store(&dst[(size_t)bs*4096 + p*64 + cp], lo | (hi << 16),
                               __ATOMIC_RELAXED, __HIP_MEMORY_SCOPE_SYSTEM);
        }
    } else if (bid < 72 && tid < 64) {
        int n = bid - 48;
        float s = blog[tid];
        for (int c = 0; c < 64; c++) s += ldw(&mf[n*64 + c]) * Wlog[c*64 + tid];
        float mx = s;
        #pragma unroll
        for (int off = 32; off >= 1; off >>= 1) mx = fmaxf(mx, __shfl_xor(mx, off, 64));
        float p = __expf(s - mx);
        float se = p;
        #pragma unroll
        for (int off = 32; off >= 1; off >>= 1) se += __shfl_xor(se, off, 64);
        int bi = n/6, si = n%6;
        int lab = (si < 5) ? sy[bi*5+si] : qy[bi];
        float s_lab = __shfl(s, lab, 64);
        if (tid == 0) stw(&rv[n], -(s_lab - mx - __logf(se)));
    }
    if (bid >= 144) {
        __syncthreads();
        if (tid == 0) postf(flag3, bid);
        return;
    }
    gbar(flag3, bid, tid);

    // ================= P5: rel + head (blocks 0..143)
    {
        int cb = bid;
        int b = cb / 36, rem = cb % 36;
        int j = rem / 6, i = rem % 6;
        int lane = tid & 63, wv8 = tid >> 6;
        int col = lane & 15, quad = lane >> 4;
        int qhalf = wv8 >> 2, pw = wv8 & 3;

        _Float16* Vsh = (_Float16*)smem;
        float* xfred = smem + 4096;
        float* xfl   = smem + 4608;
        float* hidl  = smem + 4672;

        int uimg = b*6 + i, vimg = b*6 + j;
        __syncthreads();
        {
            const u64* src = (const u64*)(V32 + (size_t)vimg*4096);
            u64 t[4];
            #pragma unroll
            for (int k = 0; k < 4; k++) t[k] = ld64(&src[k*512 + tid]);
            #pragma unroll
            for (int k = 0; k < 4; k++) ((u64*)smem)[k*512 + tid] = t[k];
        }
        f16x8 uf[4];
        {
            const u64* up = (const u64*)(U32 + (size_t)uimg*4096 + (pw*16 + col)*64 + quad*4);
            u64 t[8];
            #pragma unroll
            for (int kt = 0; kt < 4; kt++) {
                t[kt*2]   = ld64(&up[kt*8]);
                t[kt*2+1] = ld64(&up[kt*8 + 1]);
            }
            #pragma unroll
            for (int kt = 0; kt < 4; kt++) {
                u64 pair[2] = {t[kt*2], t[kt*2+1]};
                uf[kt] = __builtin_bit_cast(f16x8, pair);
            }
        }
        f16x8 bf[4][4];
        #pragma unroll
        for (int kt = 0; kt < 4; kt++)
            #pragma unroll
            for (int nt = 0; nt < 4; nt++) {
                f16x8 t;
                #pragma unroll
                for (int jj = 0; jj < 8; jj++)
                    t[jj] = (_Float16)Wg2[(kt*32 + quad*8 + jj)*64 + nt*16 + col];
                bf[kt][nt] = t;
            }
        float bgv[4];
        #pragma unroll
        for (int nt = 0; nt < 4; nt++) bgv[nt] = bg2[nt*16 + col];
        __syncthreads();

        float sums[4] = {0.f,0.f,0.f,0.f};
        for (int qq = 0; qq < 32; qq++) {
            int q = qhalf*32 + qq;
            const _Float16* vp = &Vsh[q*128 + quad*8];
            f32x4 acc[4];
            #pragma unroll
            for (int nt = 0; nt < 4; nt++)
                acc[nt] = (f32x4){bgv[nt], bgv[nt], bgv[nt], bgv[nt]};
            #pragma unroll
            for (int kt = 0; kt < 4; kt++) {
                f16x8 vf = *(const f16x8*)&vp[kt*32];
                f16x8 af = uf[kt] + vf;
                af = __builtin_elementwise_max(af, (f16x8){0,0,0,0,0,0,0,0});
                #pragma unroll
                for (int nt = 0; nt < 4; nt++)
                    acc[nt] = __builtin_amdgcn_mfma_f32_16x16x32_f16(af, bf[kt][nt], acc[nt], 0, 0, 0);
            }
            #pragma unroll
            for (int nt = 0; nt < 4; nt++)
                #pragma unroll
                for (int rr = 0; rr < 4; rr++)
                    sums[nt] += fmaxf(acc[nt][rr], 0.f);
        }
        #pragma unroll
        for (int nt = 0; nt < 4; nt++) {
            sums[nt] += __shfl_xor(sums[nt], 16, 64);
            sums[nt] += __shfl_xor(sums[nt], 32, 64);
        }
        if (lane < 16) {
            #pragma unroll
            for (int nt = 0; nt < 4; nt++) xfred[wv8*64 + nt*16 + lane] = sums[nt];
        }
        __syncthreads();
        if (tid < 64) {
            float x = 0.f;
            #pragma unroll
            for (int w8 = 0; w8 < 8; w8++) x += xfred[w8*64 + tid];
            xfl[tid] = x;
        }
        __syncthreads();
        if (tid < 16) {
            float s = bf1[tid];
            for (int c = 0; c < 64; c++) s += xfl[c]*Wf1[c*16 + tid];
            hidl[tid] = fmaxf(s, 0.f);
        }
        __syncthreads();
        if (tid == 0) {
            float sc = bf2[0];
            #pragma unroll
            for (int h = 0; h < 16; h++) sc += hidl[h]*Wf2[h];
            stw(&Pmg[cb], 1.f/(1.f + __expf(-sc)));
            postf(flagB, cb);
        }
    }

    // ================= P6: losses (block 0)
    if (bid == 0) {
        if (tid < 64) {
            int* p0 = flagB + tid;
            for (;;) {
                int ok = (__hip_atomic_load(p0, __ATOMIC_RELAXED, __HIP_MEMORY_SCOPE_SYSTEM) == 1)
                       & (__hip_atomic_load(p0+64, __ATOMIC_RELAXED, __HIP_MEMORY_SCOPE_SYSTEM) == 1)
                       & ((tid < 16) ? (__hip_atomic_load(p0+128, __ATOMIC_RELAXED, __HIP_MEMORY_SCOPE_SYSTEM) == 1) : 1);
                if (__all(ok)) break;
                __builtin_amdgcn_s_sleep(2);
            }
        }
        __syncthreads();
        asm volatile("" ::: "memory");

        float* Pmsh = smem;
        int*   lab  = (int*)(smem + 160);
        float* red  = smem + 192;
        float* ratio= smem + 768;
        if (tid < 144) Pmsh[tid] = ldw(&Pmg[tid]);
        if (tid < 24) { int bi = tid/6, si = tid%6; lab[tid] = (si < 5) ? sy[bi*5+si] : qy[bi]; }
        __syncthreads();
        float e = 0.f;
        if (tid < 144) {
            int b = tid/36, r = tid%36, jj = r/6, ii = r%6;
            float y = (lab[b*6+jj] == lab[b*6+ii]) ? 1.f : 0.f;
            float d = Pmsh[tid] - y;
            e = d*d;
        }
        red[tid] = e;
        __syncthreads();
        for (int s = 256; s > 0; s >>= 1) {
            if (tid < s) red[tid] += red[tid+s];
            __syncthreads();
        }
        if (tid < 4) {
            float s2 = 0.f, a2 = 0.f;
            for (int jj = 0; jj < 6; jj++)
                for (int ii = 0; ii < 6; ii++) {
                    float pa = Pmsh[tid*36 + jj*6 + ii], pb = Pmsh[tid*36 + ii*6 + jj];
                    float sm = 0.5f*(pa+pb), an = 0.5f*(pa-pb);
                    s2 += sm*sm; a2 += an*an;
                }
            float sn = sqrtf(s2), anq = sqrtf(a2);
            ratio[tid] = (sn - anq)/(sn + anq);
        }
        __syncthreads();
        if (tid == 0) {
            float sl = 0.25f*(ratio[0]+ratio[1]+ratio[2]+ratio[3]);
            float euc = red[0] * (1.f/144.f);
            float cs = 0.f;
            for (int k = 0; k < 24; k++) cs += ldw(&rv[k]);
            out[0] = cs * (1.f/24.f);
            out[1] = euc - 0.1f*sl;
            out[2] = sl;
        }
    }
}

extern "C" void kernel_launch(void* const* d_in, const int* in_sizes, int n_in,
                              void* d_out, int out_size, void* d_ws, size_t ws_size,
                              hipStream_t stream) {
    (void)in_sizes; (void)n_in; (void)out_size; (void)ws_size;
    const float* sx   = (const float*)d_in[0];
    const int*   sy   = (const int*)  d_in[1];
    const float* qx   = (const float*)d_in[2];
    const int*   qy   = (const int*)  d_in[3];
    const float* k1   = (const float*)d_in[4];
    const float* bc1  = (const float*)d_in[5];
    const float* k2   = (const float*)d_in[6];
    const float* bc2  = (const float*)d_in[7];
    const float* k3   = (const float*)d_in[8];
    const float* bc3  = (const float*)d_in[9];
    const float* Wlog = (const float*)d_in[10];
    const float* blog = (const float*)d_in[11];
    const float* Wg1  = (const float*)d_in[12];
    const float* bg1  = (const float*)d_in[13];
    const float* Wg2  = (const float*)d_in[14];
    const float* bg2  = (const float*)d_in[15];
    const float* Wf1  = (const float*)d_in[16];
    const float* bf1  = (const float*)d_in[17];
    const float* Wf2  = (const float*)d_in[18];
    const float* bf2  = (const float*)d_in[19];
    float* ws  = (float*)d_ws;
    float* out = (float*)d_out;

    mega4_k<<<NB, 512, 0, stream>>>(sx, sy, qx, qy, k1, bc1, k2, bc2,
                                    k3, bc3, Wlog, blog, Wg1, bg1, Wg2, bg2,
                                    Wf1, bf1, Wf2, bf2, ws, out);
}

// Round 7
// 288.027 us; speedup vs baseline: 1.4754x; 1.4754x over previous
//
#include <hip/hip_runtime.h>

typedef _Float16 f16x8 __attribute__((ext_vector_type(8)));
typedef float f32x4 __attribute__((ext_vector_type(4)));
typedef unsigned u32x4 __attribute__((ext_vector_type(4)));

// ---- IF-coherent accessors: 32-BIT ONLY relaxed system-scope atomics.
// (R6 lesson: 64-bit system-scope atomic loads lower to RMW -> 300MB HBM writes.)
__device__ __forceinline__ float ldw(const float* p) {
    return __uint_as_float(__hip_atomic_load((unsigned*)p, __ATOMIC_RELAXED,
                                             __HIP_MEMORY_SCOPE_SYSTEM));
}
__device__ __forceinline__ void stw(float* p, float x) {
    __hip_atomic_store((unsigned*)p, __float_as_uint(x), __ATOMIC_RELAXED,
                       __HIP_MEMORY_SCOPE_SYSTEM);
}
__device__ __forceinline__ unsigned ldu(const unsigned* p) {
    return __hip_atomic_load((unsigned*)p, __ATOMIC_RELAXED, __HIP_MEMORY_SCOPE_SYSTEM);
}
__device__ __forceinline__ void stu(unsigned* p, unsigned x) {
    __hip_atomic_store(p, x, __ATOMIC_RELAXED, __HIP_MEMORY_SCOPE_SYSTEM);
}
__device__ __forceinline__ void postf(int* fl, int idx) {
    asm volatile("s_waitcnt vmcnt(0) lgkmcnt(0)" ::: "memory");
    __hip_atomic_store(fl + idx, 1, __ATOMIC_RELAXED, __HIP_MEMORY_SCOPE_SYSTEM);
}
__device__ __forceinline__ int ldflag(const int* fl, int idx) {
    return __hip_atomic_load(fl + idx, __ATOMIC_RELAXED, __HIP_MEMORY_SCOPE_SYSTEM);
}

// Grid 144 x 512. Blocks 0..23: full per-image pipeline (conv1/2/3 + meanpool +
// uv + cls) entirely in LDS -> UC-store U,V,rv -> flagC[img].
// Blocks 0..143: poll flagC for their 2 images -> rel MFMA + head -> Pm, flagB.
// Block 0: poll flagB -> losses.
__global__ void __launch_bounds__(512) mega5_k(
    const float* __restrict__ sx, const int* __restrict__ sy,
    const float* __restrict__ qx, const int* __restrict__ qy,
    const float* __restrict__ k1, const float* __restrict__ bc1,
    const float* __restrict__ k2, const float* __restrict__ bc2,
    const float* __restrict__ k3, const float* __restrict__ bc3,
    const float* __restrict__ Wlog, const float* __restrict__ blog,
    const float* __restrict__ Wg1, const float* __restrict__ bg1,
    const float* __restrict__ Wg2, const float* __restrict__ bg2,
    const float* __restrict__ Wf1, const float* __restrict__ bf1,
    const float* __restrict__ Wf2, const float* __restrict__ bf2,
    float* __restrict__ ws, float* __restrict__ out)
{
    __shared__ __align__(16) float smem[32768];   // 128 KB
    const int tid = threadIdx.x;
    const int bid = blockIdx.x;

    float* rv    = ws;                       // 24
    float* Pmg   = rv + 64;                  // 144
    unsigned* U32 = (unsigned*)(Pmg + 160);  // 24 imgs x 4096 u32
    unsigned* V32 = U32 + 24*4096;
    int* flagC   = (int*)(V32 + 24*4096);    // 24
    int* flagB   = flagC + 64;               // 144

    // ======================= per-image pipeline (blocks 0..23)
    if (bid < 24) {
        const int n = bid;
        const int bi = n / 6, si = n % 6;
        const float* inp = (si < 5) ? sx + (size_t)((bi*5+si)*3)*4096
                                    : qx + (size_t)(bi*3)*4096;
        // ---- conv1 -> feat1 [32][32][32] fp32 in smem[0..32767]
        #pragma unroll
        for (int half = 0; half < 2; half++) {
            int px = tid + half*512;
            int oy = px >> 5, ox = px & 31;
            float tap[27];
            #pragma unroll
            for (int ic = 0; ic < 3; ic++)
                #pragma unroll
                for (int dy = 0; dy < 3; dy++)
                    #pragma unroll
                    for (int dx = 0; dx < 3; dx++) {
                        int iy = 2*oy+dy, ix = 2*ox+dx;
                        tap[ic*9+dy*3+dx] = (iy < 64 && ix < 64) ? inp[ic*4096 + iy*64 + ix] : 0.f;
                    }
            for (int oc = 0; oc < 32; oc++) {
                float a = bc1[oc];
                #pragma unroll
                for (int t = 0; t < 27; t++) a += tap[t]*k1[oc*27 + t];
                smem[oc*1024 + px] = fmaxf(a, 0.f);
            }
        }
        __syncthreads();

        // ---- conv2: accumulate in regs (feat1 stays live), 24 oc per thread
        {
            int px = tid & 255, grp = tid >> 8;          // grp 0/1 -> oc 0..23 / 24..47
            int oy = px >> 4, ox = px & 15;
            float acc[24];
            #pragma unroll
            for (int o = 0; o < 24; o++) acc[o] = bc2[grp*24 + o];
            for (int ic = 0; ic < 32; ic++) {
                float tap[9];
                #pragma unroll
                for (int dy = 0; dy < 3; dy++)
                    #pragma unroll
                    for (int dx = 0; dx < 3; dx++) {
                        int iy = 2*oy+dy, ix = 2*ox+dx;
                        tap[dy*3+dx] = (iy < 32 && ix < 32) ? smem[ic*1024 + iy*32 + ix] : 0.f;
                    }
                #pragma unroll
                for (int o = 0; o < 24; o++) {
                    const float* wp = k2 + (size_t)(grp*24 + o)*288 + ic*9;
                    #pragma unroll
                    for (int t = 0; t < 9; t++) acc[o] += tap[t]*wp[t];
                }
            }
            __syncthreads();                    // feat1 reads complete
            #pragma unroll
            for (int o = 0; o < 24; o++)        // feat2 [48][256] at smem[0..12287]
                smem[(grp*24 + o)*256 + px] = fmaxf(acc[o], 0.f);
        }
        __syncthreads();

        // ---- conv3 + meanpool: feat3 [64][64] at smem[16384..], mf at smem[20480..]
        {
            int px3 = tid & 63, grp3 = tid >> 6;        // wave w == grp3 w
            int oy = px3 >> 3, ox = px3 & 7;
            float a3[8];
            #pragma unroll
            for (int o = 0; o < 8; o++) a3[o] = bc3[grp3*8 + o];
            for (int ic = 0; ic < 48; ic++) {
                float tap[9];
                #pragma unroll
                for (int dy = 0; dy < 3; dy++)
                    #pragma unroll
                    for (int dx = 0; dx < 3; dx++) {
                        int iy = 2*oy+dy, ix = 2*ox+dx;
                        tap[dy*3+dx] = (iy < 16 && ix < 16) ? smem[ic*256 + iy*16 + ix] : 0.f;
                    }
                #pragma unroll
                for (int o = 0; o < 8; o++) {
                    const float* wp = k3 + (size_t)(grp3*8 + o)*432 + ic*9;
                    #pragma unroll
                    for (int t = 0; t < 9; t++) a3[o] += tap[t]*wp[t];
                }
            }
            #pragma unroll
            for (int o = 0; o < 8; o++) {
                float r = fmaxf(a3[o], 0.f);
                smem[16384 + (grp3*8 + o)*64 + px3] = r;   // feat3 (disjoint from feat2)
                #pragma unroll
                for (int off = 32; off >= 1; off >>= 1) r += __shfl_xor(r, off, 64);
                if (px3 == 0) smem[20480 + grp3*8 + o] = r * (1.f/64.f);
            }
        }
        __syncthreads();

        // ---- uv: u/v (64p x 128col) f16 -> UC store packed pairs
        {
            int cp  = tid & 63;            // col pair 2cp,2cp+1 (lane id -> broadcast LDS reads)
            int sel = (tid >> 6) & 1;      // 0=u 1=v (wave-uniform)
            int pq  = tid >> 7;            // 0..3 -> p block of 16
            int pbase = pq*16;
            float a0[16], a1[16];
            float b0 = sel ? bg1[2*cp] : 0.f;
            float b1 = sel ? bg1[2*cp+1] : 0.f;
            #pragma unroll
            for (int k = 0; k < 16; k++) { a0[k] = b0; a1[k] = b1; }
            const float* Wc = Wg1 + sel*66*128 + 2*cp;
            for (int c = 0; c < 64; c++) {
                float w0 = Wc[c*128], w1 = Wc[c*128 + 1];
                #pragma unroll
                for (int k = 0; k < 16; k++) {
                    float a = smem[16384 + c*64 + pbase + k];
                    a0[k] += a*w0; a1[k] += a*w1;
                }
            }
            #pragma unroll
            for (int c = 64; c < 66; c++) {
                float w0 = Wc[c*128], w1 = Wc[c*128 + 1];
                #pragma unroll
                for (int k = 0; k < 16; k++) {
                    int p = pbase + k;
                    float a = (c == 64) ? (float)(p>>3)*0.125f : (float)(p&7)*0.125f;
                    a0[k] += a*w0; a1[k] += a*w1;
                }
            }
            unsigned* dst = (sel ? V32 : U32) + (size_t)n*4096;
            #pragma unroll
            for (int k = 0; k < 16; k++) {
                int p = pbase + k;
                unsigned lo = (unsigned)__builtin_bit_cast(unsigned short, (_Float16)a0[k]);
                unsigned hi = (unsigned)__builtin_bit_cast(unsigned short, (_Float16)a1[k]);
                stu(&dst[p*64 + cp], lo | (hi << 16));
            }
        }
        // ---- cls head for this image (mf in LDS)
        if (tid < 64) {
            float s = blog[tid];
            for (int c = 0; c < 64; c++) s += smem[20480 + c] * Wlog[c*64 + tid];
            float mx = s;
            #pragma unroll
            for (int off = 32; off >= 1; off >>= 1) mx = fmaxf(mx, __shfl_xor(mx, off, 64));
            float p = __expf(s - mx);
            float se = p;
            #pragma unroll
            for (int off = 32; off >= 1; off >>= 1) se += __shfl_xor(se, off, 64);
            int lab = (si < 5) ? sy[bi*5+si] : qy[bi];
            float s_lab = __shfl(s, lab, 64);
            if (tid == 0) stw(&rv[n], -(s_lab - mx - __logf(se)));
        }
        __syncthreads();
        if (tid == 0) postf(flagC, n);      // vmcnt(0) drains U,V,rv UC stores
    }

    // ======================= relation phase (blocks 0..143)
    {
        int cb = bid;
        int b = cb / 36, rem = cb % 36;
        int j = rem / 6, i = rem % 6;
        int uimg = b*6 + i, vimg = b*6 + j;

        if (tid == 0) {
            while (!(ldflag(flagC, uimg) == 1 && ldflag(flagC, vimg) == 1))
                __builtin_amdgcn_s_sleep(2);
        }
        __syncthreads();
        asm volatile("" ::: "memory");

        int lane = tid & 63, wv8 = tid >> 6;
        int col = lane & 15, quad = lane >> 4;
        int qhalf = wv8 >> 2, pw = wv8 & 3;

        _Float16* Vsh = (_Float16*)smem;     // 8192 halves = 4096 u32
        unsigned* Vsh32 = (unsigned*)smem;
        float* xfred = smem + 4096;
        float* xfl   = smem + 4608;
        float* hidl  = smem + 4672;

        {   // batched 32-bit UC staging of V
            const unsigned* src = V32 + (size_t)vimg*4096;
            unsigned t[8];
            #pragma unroll
            for (int k = 0; k < 8; k++) t[k] = ldu(&src[k*512 + tid]);
            #pragma unroll
            for (int k = 0; k < 8; k++) Vsh32[k*512 + tid] = t[k];
        }
        f16x8 uf[4];
        {   // batched 32-bit UC load of this lane's fixed U slice
            const unsigned* up = U32 + (size_t)uimg*4096 + (pw*16 + col)*64 + quad*4;
            unsigned t[16];
            #pragma unroll
            for (int kt = 0; kt < 4; kt++)
                #pragma unroll
                for (int r = 0; r < 4; r++) t[kt*4+r] = ldu(&up[kt*16 + r]);
            #pragma unroll
            for (int kt = 0; kt < 4; kt++) {
                u32x4 q4 = {t[kt*4], t[kt*4+1], t[kt*4+2], t[kt*4+3]};
                uf[kt] = __builtin_bit_cast(f16x8, q4);
            }
        }
        f16x8 bf[4][4];
        #pragma unroll
        for (int kt = 0; kt < 4; kt++)
            #pragma unroll
            for (int nt = 0; nt < 4; nt++) {
                f16x8 t;
                #pragma unroll
                for (int jj = 0; jj < 8; jj++)
                    t[jj] = (_Float16)Wg2[(kt*32 + quad*8 + jj)*64 + nt*16 + col];
                bf[kt][nt] = t;
            }
        float bgv[4];
        #pragma unroll
        for (int nt = 0; nt < 4; nt++) bgv[nt] = bg2[nt*16 + col];
        __syncthreads();

        float sums[4] = {0.f,0.f,0.f,0.f};
        for (int qq = 0; qq < 32; qq++) {
            int q = qhalf*32 + qq;
            const _Float16* vp = &Vsh[q*128 + quad*8];
            f32x4 acc[4];
            #pragma unroll
            for (int nt = 0; nt < 4; nt++)
                acc[nt] = (f32x4){bgv[nt], bgv[nt], bgv[nt], bgv[nt]};
            #pragma unroll
            for (int kt = 0; kt < 4; kt++) {
                f16x8 vf = *(const f16x8*)&vp[kt*32];
                f16x8 af = uf[kt] + vf;
                af = __builtin_elementwise_max(af, (f16x8){0,0,0,0,0,0,0,0});
                #pragma unroll
                for (int nt = 0; nt < 4; nt++)
                    acc[nt] = __builtin_amdgcn_mfma_f32_16x16x32_f16(af, bf[kt][nt], acc[nt], 0, 0, 0);
            }
            #pragma unroll
            for (int nt = 0; nt < 4; nt++)
                #pragma unroll
                for (int rr = 0; rr < 4; rr++)
                    sums[nt] += fmaxf(acc[nt][rr], 0.f);
        }
        #pragma unroll
        for (int nt = 0; nt < 4; nt++) {
            sums[nt] += __shfl_xor(sums[nt], 16, 64);
            sums[nt] += __shfl_xor(sums[nt], 32, 64);
        }
        if (lane < 16) {
            #pragma unroll
            for (int nt = 0; nt < 4; nt++) xfred[wv8*64 + nt*16 + lane] = sums[nt];
        }
        __syncthreads();
        if (tid < 64) {
            float x = 0.f;
            #pragma unroll
            for (int w8 = 0; w8 < 8; w8++) x += xfred[w8*64 + tid];
            xfl[tid] = x;
        }
        __syncthreads();
        if (tid < 16) {
            float s = bf1[tid];
            for (int c = 0; c < 64; c++) s += xfl[c]*Wf1[c*16 + tid];
            hidl[tid] = fmaxf(s, 0.f);
        }
        __syncthreads();
        if (tid == 0) {
            float sc = bf2[0];
            #pragma unroll
            for (int h = 0; h < 16; h++) sc += hidl[h]*Wf2[h];
            stw(&Pmg[cb], 1.f/(1.f + __expf(-sc)));
            postf(flagB, cb);
        }
    }

    // ======================= losses (block 0)
    if (bid == 0) {
        if (tid < 64) {
            const int* p0 = flagB + tid;
            for (;;) {
                int ok = (ldflag(p0, 0) == 1) & (ldflag(p0, 64) == 1)
                       & ((tid < 16) ? (ldflag(p0, 128) == 1) : 1);
                if (__all(ok)) break;
                __builtin_amdgcn_s_sleep(2);
            }
        }
        __syncthreads();
        asm volatile("" ::: "memory");

        float* Pmsh = smem;
        int*   lab  = (int*)(smem + 160);
        float* red  = smem + 192;
        float* ratio= smem + 768;
        if (tid < 144) Pmsh[tid] = ldw(&Pmg[tid]);
        if (tid < 24) { int bi = tid/6, si = tid%6; lab[tid] = (si < 5) ? sy[bi*5+si] : qy[bi]; }
        __syncthreads();
        float e = 0.f;
        if (tid < 144) {
            int b = tid/36, r = tid%36, jj = r/6, ii = r%6;
            float y = (lab[b*6+jj] == lab[b*6+ii]) ? 1.f : 0.f;
            float d = Pmsh[tid] - y;
            e = d*d;
        }
        red[tid] = e;
        __syncthreads();
        for (int s = 256; s > 0; s >>= 1) {
            if (tid < s) red[tid] += red[tid+s];
            __syncthreads();
        }
        if (tid < 4) {
            float s2 = 0.f, a2 = 0.f;
            for (int jj = 0; jj < 6; jj++)
                for (int ii = 0; ii < 6; ii++) {
                    float pa = Pmsh[tid*36 + jj*6 + ii], pb = Pmsh[tid*36 + ii*6 + jj];
                    float sm = 0.5f*(pa+pb), an = 0.5f*(pa-pb);
                    s2 += sm*sm; a2 += an*an;
                }
            float sn = sqrtf(s2), anq = sqrtf(a2);
            ratio[tid] = (sn - anq)/(sn + anq);
        }
        __syncthreads();
        if (tid == 0) {
            float sl = 0.25f*(ratio[0]+ratio[1]+ratio[2]+ratio[3]);
            float euc = red[0] * (1.f/144.f);
            float cs = 0.f;
            for (int k = 0; k < 24; k++) cs += ldw(&rv[k]);
            out[0] = cs * (1.f/24.f);
            out[1] = euc - 0.1f*sl;
            out[2] = sl;
        }
    }
}

extern "C" void kernel_launch(void* const* d_in, const int* in_sizes, int n_in,
                              void* d_out, int out_size, void* d_ws, size_t ws_size,
                              hipStream_t stream) {
    (void)in_sizes; (void)n_in; (void)out_size; (void)ws_size;
    const float* sx   = (const float*)d_in[0];
    const int*   sy   = (const int*)  d_in[1];
    const float* qx   = (const float*)d_in[2];
    const int*   qy   = (const int*)  d_in[3];
    const float* k1   = (const float*)d_in[4];
    const float* bc1  = (const float*)d_in[5];
    const float* k2   = (const float*)d_in[6];
    const float* bc2  = (const float*)d_in[7];
    const float* k3   = (const float*)d_in[8];
    const float* bc3  = (const float*)d_in[9];
    const float* Wlog = (const float*)d_in[10];
    const float* blog = (const float*)d_in[11];
    const float* Wg1  = (const float*)d_in[12];
    const float* bg1  = (const float*)d_in[13];
    const float* Wg2  = (const float*)d_in[14];
    const float* bg2  = (const float*)d_in[15];
    const float* Wf1  = (const float*)d_in[16];
    const float* bf1  = (const float*)d_in[17];
    const float* Wf2  = (const float*)d_in[18];
    const float* bf2  = (const float*)d_in[19];
    float* ws  = (float*)d_ws;
    float* out = (float*)d_out;

    mega5_k<<<144, 512, 0, stream>>>(sx, sy, qx, qy, k1, bc1, k2, bc2,
                                     k3, bc3, Wlog, blog, Wg1, bg1, Wg2, bg2,
                                     Wf1, bf1, Wf2, bf2, ws, out);
}